// Round 1
// baseline (683.822 us; speedup 1.0000x reference)
//
#include <hip/hip_runtime.h>

// Sliding-window attention, MI355X/gfx950. Round 6.
// Pipeline: convert x->bf16, convert+transpose weights -> bf16;
// m97 MFMA GEMM (qkv, bf16 out) -> V transpose -> flash windowed attention
// -> m97 GEMM with FP32 epilogue into d_out. ws usage: 200 MB.
//
// R6 change: attn_win restructured barrier-free. K/V per (bn,h) are 64KB each
// (L1/L2-resident, re-read by all waves anyway), so Qs/Ks/Vs LDS staging and
// ALL __syncthreads are removed; operand fragments come straight from global.
// The bytes fed to each MFMA are identical to the R5-verified kernel — only
// the sourcing changed. LDS 80KB->32KB (wave-private P only), launch_bounds
// (256,3) for 3 waves/SIMD. s_setprio(1) around MFMA clusters (T5, m191).

typedef unsigned short u16;
typedef unsigned int u32;
typedef __attribute__((ext_vector_type(8))) short bf16x8;   // 8 x bf16 (4 VGPRs)
typedef __attribute__((ext_vector_type(4))) float f32x4;

__device__ __forceinline__ float bf2f(u16 v) {
  union { u32 u; float f; } t; t.u = ((u32)v) << 16; return t.f;
}
__device__ __forceinline__ u16 f2bf(float f) {
  union { float f; u32 u; } t; t.f = f;
  u32 u = t.u + 0x7fffu + ((t.u >> 16) & 1u);   // RNE
  return (u16)(u >> 16);
}
__device__ __forceinline__ void g2lds16(const void* g, void* l) {
  __builtin_amdgcn_global_load_lds((const __attribute__((address_space(1))) void*)g,
                                   (__attribute__((address_space(3))) void*)l,
                                   16, 0, 0);
}

// ---------------------------------------------------------------------------
// x [16384][1024] fp32 -> bf16, flat
// ---------------------------------------------------------------------------
__global__ __launch_bounds__(256) void canon_x(
    const float* __restrict__ xf, u16* __restrict__ xb) {
  size_t i = ((size_t)blockIdx.x * 256 + threadIdx.x) * 8;
  float4 a = *(const float4*)(xf + i);
  float4 b = *(const float4*)(xf + i + 4);
  u16 o[8] = { f2bf(a.x), f2bf(a.y), f2bf(a.z), f2bf(a.w),
               f2bf(b.x), f2bf(b.y), f2bf(b.z), f2bf(b.w) };
  *(bf16x8*)(xb + i) = *(bf16x8*)o;
}

// ---------------------------------------------------------------------------
// Weight transpose+convert: in [R][C] fp32 -> out [C][R] bf16
// ---------------------------------------------------------------------------
__global__ __launch_bounds__(256) void transpose_w(
    const float* __restrict__ in, u16* __restrict__ out, int R, int C) {
  __shared__ u16 tile[32][33];
  int c0 = blockIdx.x * 32, r0 = blockIdx.y * 32;
  int tx = threadIdx.x & 31, ty = threadIdx.x >> 5;
#pragma unroll
  for (int i = 0; i < 32; i += 8)
    tile[ty + i][tx] = f2bf(in[(size_t)(r0 + ty + i) * C + c0 + tx]);
  __syncthreads();
#pragma unroll
  for (int i = 0; i < 32; i += 8)
    out[(size_t)(c0 + ty + i) * R + r0 + tx] = tile[tx][ty + i];
}

// ---------------------------------------------------------------------------
// V part of qkv [16384][3072] -> Vt [bh=512][d=64][t=512]   (bf16)
// ---------------------------------------------------------------------------
__global__ __launch_bounds__(256) void transpose_v(
    const u16* __restrict__ qkv, u16* __restrict__ vt) {
  __shared__ u16 tile[32][33];
  int bh = blockIdx.z, bn = bh >> 4, h = bh & 15;
  int t0 = blockIdx.x * 32, d0 = blockIdx.y * 32;
  int tx = threadIdx.x & 31, ty = threadIdx.x >> 5;
  const u16* src = qkv + (size_t)(bn * 512) * 3072 + 2048 + h * 64;
#pragma unroll
  for (int i = 0; i < 32; i += 8)
    tile[ty + i][tx] = src[(size_t)(t0 + ty + i) * 3072 + d0 + tx];
  __syncthreads();
  u16* dst = vt + ((size_t)bh * 64 + d0) * 512 + t0;
#pragma unroll
  for (int i = 0; i < 32; i += 8)
    dst[(size_t)(ty + i) * 512 + tx] = tile[tx][ty + i];
}

// ---------------------------------------------------------------------------
// C[M,N] = A[M,K](bf16) * Bt[N,K]^T(bf16) + bias[N](fp32); OutT u16|float.
// m97 structure: 128x128 tile, BK=32, 2x2 waves of 64x64, global_load_lds w=16.
// ---------------------------------------------------------------------------
template <typename OutT>
__global__ __launch_bounds__(256, 2) void gemm_bt_bias(
    const u16* __restrict__ A, const u16* __restrict__ Bt,
    const float* __restrict__ bias, OutT* __restrict__ C,
    int M, int N, int K) {
  __shared__ __align__(16) u16 As[128 * 32];
  __shared__ __align__(16) u16 Bs[128 * 32];
  const int tid = threadIdx.x;
  const int wave = tid >> 6, lane = tid & 63;
  const int quad = lane >> 4, l16 = lane & 15;
  const int m0 = blockIdx.y * 128, n0 = blockIdx.x * 128;
  const int wm = (wave >> 1) * 64, wn = (wave & 1) * 64;

  f32x4 acc[4][4] = {};

  int e0 = (wave * 512) + lane * 8;   // chunk 0 element offset in 128x32 tile
  int e1 = 2048 + e0;                 // chunk 1
  int rA0 = e0 >> 5, cA0 = e0 & 31;
  int rA1 = e1 >> 5, cA1 = e1 & 31;
  const u16* ga0 = A + (size_t)(m0 + rA0) * K + cA0;
  const u16* ga1 = A + (size_t)(m0 + rA1) * K + cA1;
  const u16* gb0 = Bt + (size_t)(n0 + rA0) * K + cA0;
  const u16* gb1 = Bt + (size_t)(n0 + rA1) * K + cA1;
  u16* As0 = As + (size_t)wave * 512;
  u16* As1 = As0 + 2048;
  u16* Bs0 = Bs + (size_t)wave * 512;
  u16* Bs1 = Bs0 + 2048;

  for (int k0 = 0; k0 < K; k0 += 32) {
    g2lds16(ga0 + k0, As0);
    g2lds16(ga1 + k0, As1);
    g2lds16(gb0 + k0, Bs0);
    g2lds16(gb1 + k0, Bs1);
    __syncthreads();
    bf16x8 a[4], b[4];
#pragma unroll
    for (int mi = 0; mi < 4; ++mi)
      a[mi] = *(const bf16x8*)(As + (wm + mi * 16 + l16) * 32 + quad * 8);
#pragma unroll
    for (int ni = 0; ni < 4; ++ni)
      b[ni] = *(const bf16x8*)(Bs + (wn + ni * 16 + l16) * 32 + quad * 8);
#pragma unroll
    for (int mi = 0; mi < 4; ++mi)
#pragma unroll
      for (int ni = 0; ni < 4; ++ni)
        acc[mi][ni] = __builtin_amdgcn_mfma_f32_16x16x32_bf16(a[mi], b[ni], acc[mi][ni], 0, 0, 0);
    __syncthreads();
  }

  // epilogue: C/D layout col=l16, row=quad*4+reg
#pragma unroll
  for (int ni = 0; ni < 4; ++ni) {
    int col = n0 + wn + ni * 16 + l16;
    float bv = bias[col];
#pragma unroll
    for (int mi = 0; mi < 4; ++mi) {
      int row = m0 + wm + mi * 16 + quad * 4;
#pragma unroll
      for (int r = 0; r < 4; ++r) {
        float v = acc[mi][ni][r] + bv;
        if constexpr (sizeof(OutT) == 2)
          C[(size_t)(row + r) * N + col] = f2bf(v);
        else
          C[(size_t)(row + r) * N + col] = v;
      }
    }
  }
}

// ---------------------------------------------------------------------------
// Windowed causal flash attention. Grid (qt=4, h=16, bn=32), 256 threads.
// R6: barrier-free. Q in registers; K/V operand fragments direct from
// global (L1/L2-resident: 64KB K + 64KB Vt per (bn,h)). Only LDS is the
// wave-private P buffer (32KB total) -> no __syncthreads anywhere.
// Operand bytes per MFMA identical to R5-verified kernel.
// ---------------------------------------------------------------------------
__global__ __launch_bounds__(256, 3) void attn_win(
    const u16* __restrict__ qkv, const u16* __restrict__ vt,
    u16* __restrict__ attn) {
  __shared__ __align__(16) u16 Ps[4][32 * 128];

  const int qt = blockIdx.x, h = blockIdx.y, bn = blockIdx.z;
  const int bh = bn * 16 + h;
  const int tid = threadIdx.x;
  const int wave = tid >> 6, lane = tid & 63;
  const int quad = lane >> 4, l16 = lane & 15;
  const int t0 = bn * 512 + qt * 128;

  // ---- Q operand fragments, direct from global: aq[mi][ks] =
  //      Q[t0 + wave*32 + mi*16 + l16][ks*32 + quad*8 .. +7]  (head h)
  bf16x8 aq[2][2];
#pragma unroll
  for (int mi = 0; mi < 2; ++mi)
#pragma unroll
    for (int ks = 0; ks < 2; ++ks)
      aq[mi][ks] = *(const bf16x8*)(
          qkv + (size_t)(t0 + wave * 32 + mi * 16 + l16) * 3072 + h * 64 + ks * 32 + quad * 8);

  float mrun[2][4], lrun[2][4];
  f32x4 o[2][4] = {};
#pragma unroll
  for (int mi = 0; mi < 2; ++mi)
#pragma unroll
    for (int r = 0; r < 4; ++r) { mrun[mi][r] = -1e30f; lrun[mi][r] = 0.f; }

  const float cexp = 0.18033688011112042f;  // (1/sqrt(64)) * log2(e)

  const u16* Kb = qkv + 1024 + h * 64;            // K[t][d] = Kb[t*3072 + d]
  const u16* Vb = vt + (size_t)bh * 64 * 512;     // Vt[d][t] = Vb[d*512 + t]
  u16* pw = &Ps[wave][0];

  for (int j = 0; j <= qt; ++j) {
    const int tk = bn * 512 + j * 128;

    // ---- S = Q K^T (this wave: rows [wave*32, +32)); K rows from global ----
    f32x4 s[2][8] = {};
    __builtin_amdgcn_s_setprio(1);
#pragma unroll
    for (int ks = 0; ks < 2; ++ks) {
#pragma unroll
      for (int ni = 0; ni < 8; ++ni) {
        bf16x8 bk = *(const bf16x8*)(
            Kb + (size_t)(tk + ni * 16 + l16) * 3072 + ks * 32 + quad * 8);
        s[0][ni] = __builtin_amdgcn_mfma_f32_16x16x32_bf16(aq[0][ks], bk, s[0][ni], 0, 0, 0);
        s[1][ni] = __builtin_amdgcn_mfma_f32_16x16x32_bf16(aq[1][ks], bk, s[1][ni], 0, 0, 0);
      }
    }
    __builtin_amdgcn_s_setprio(0);

    // ---- online softmax (C layout: col=l16, row=quad*4+r) ----
    const bool diag = (j == qt);
#pragma unroll
    for (int mi = 0; mi < 2; ++mi) {
#pragma unroll
      for (int r = 0; r < 4; ++r) {
        int m = wave * 32 + mi * 16 + quad * 4 + r;
        float rmax = -1e30f;
#pragma unroll
        for (int ni = 0; ni < 8; ++ni) {
          float v = s[mi][ni][r] * cexp;
          if (diag && (ni * 16 + l16 > m)) v = -1e30f;
          s[mi][ni][r] = v;
          rmax = fmaxf(rmax, v);
        }
        rmax = fmaxf(rmax, __shfl_xor(rmax, 1));
        rmax = fmaxf(rmax, __shfl_xor(rmax, 2));
        rmax = fmaxf(rmax, __shfl_xor(rmax, 4));
        rmax = fmaxf(rmax, __shfl_xor(rmax, 8));
        float mnew = fmaxf(mrun[mi][r], rmax);
        float alpha = exp2f(mrun[mi][r] - mnew);
        mrun[mi][r] = mnew;
        float rsum = 0.f;
#pragma unroll
        for (int ni = 0; ni < 8; ++ni) {
          float pv = exp2f(s[mi][ni][r] - mnew);
          s[mi][ni][r] = pv;
          rsum += pv;
        }
        rsum += __shfl_xor(rsum, 1);
        rsum += __shfl_xor(rsum, 2);
        rsum += __shfl_xor(rsum, 4);
        rsum += __shfl_xor(rsum, 8);
        lrun[mi][r] = lrun[mi][r] * alpha + rsum;
#pragma unroll
        for (int di = 0; di < 4; ++di) o[mi][di][r] *= alpha;
      }
    }

    // ---- P (C layout) -> wave-private LDS in A layout, swz ^(row&15) ----
    // Wave-private: no barrier needed (same-wave LDS RAW via lgkmcnt).
#pragma unroll
    for (int mi = 0; mi < 2; ++mi)
#pragma unroll
      for (int ni = 0; ni < 8; ++ni)
#pragma unroll
        for (int r = 0; r < 4; ++r) {
          int row = mi * 16 + quad * 4 + r;
          int col = ni * 16 + l16;
          int phys = (col >> 3) ^ (row & 15);
          pw[row * 128 + phys * 8 + (col & 7)] = f2bf(s[mi][ni][r]);
        }

    // ---- O += P V; Vt rows from global ----
    __builtin_amdgcn_s_setprio(1);
#pragma unroll
    for (int ks = 0; ks < 4; ++ks) {
      bf16x8 ap[2];
#pragma unroll
      for (int mi = 0; mi < 2; ++mi) {
        int row = mi * 16 + l16;
        ap[mi] = *(const bf16x8*)(pw + row * 128 + (((ks * 4 + quad) ^ (row & 15)) * 8));
      }
#pragma unroll
      for (int di = 0; di < 4; ++di) {
        bf16x8 bv = *(const bf16x8*)(
            Vb + (size_t)(di * 16 + l16) * 512 + j * 128 + ks * 32 + quad * 8);
        o[0][di] = __builtin_amdgcn_mfma_f32_16x16x32_bf16(ap[0], bv, o[0][di], 0, 0, 0);
        o[1][di] = __builtin_amdgcn_mfma_f32_16x16x32_bf16(ap[1], bv, o[1][di], 0, 0, 0);
      }
    }
    __builtin_amdgcn_s_setprio(0);
  }

  // ---- epilogue: O / l -> attn [token][h*64+d] (bf16) ----
#pragma unroll
  for (int mi = 0; mi < 2; ++mi)
#pragma unroll
    for (int r = 0; r < 4; ++r) {
      float inv = 1.0f / lrun[mi][r];
      int trow = t0 + wave * 32 + mi * 16 + quad * 4 + r;
#pragma unroll
      for (int di = 0; di < 4; ++di)
        attn[(size_t)trow * 1024 + h * 64 + di * 16 + l16] = f2bf(o[mi][di][r] * inv);
    }
}

// ---------------------------------------------------------------------------
extern "C" void kernel_launch(void* const* d_in, const int* in_sizes, int n_in,
                              void* d_out, int out_size, void* d_ws, size_t ws_size,
                              hipStream_t stream) {
  (void)in_sizes; (void)n_in; (void)out_size; (void)ws_size;
  const float* x     = (const float*)d_in[0];   // [16384][1024] fp32
  const float* w_qkv = (const float*)d_in[1];   // [1024][3072] fp32
  const float* b_qkv = (const float*)d_in[2];   // [3072] fp32
  const float* w_o   = (const float*)d_in[3];   // [1024][1024] fp32
  const float* b_o   = (const float*)d_in[4];   // [1024] fp32
  float* out = (float*)d_out;                   // [16384][1024] fp32

  char* ws = (char*)d_ws;
  u16* qkv   = (u16*)(ws + 0);            // 96 MB
  u16* vtb   = (u16*)(ws + 100663296);    // 32 MB
  u16* attnb = (u16*)(ws + 134217728);    // 32 MB
  u16* xb    = (u16*)(ws + 167772160);    // 32 MB
  u16* wqkvT = (u16*)(ws + 201326592);    // 6 MB
  u16* woT   = (u16*)(ws + 207618048);    // 2 MB  (total 200 MB)

  canon_x<<<8192, 256, 0, stream>>>(x, xb);
  transpose_w<<<dim3(96, 32), 256, 0, stream>>>(w_qkv, wqkvT, 1024, 3072);
  transpose_w<<<dim3(32, 32), 256, 0, stream>>>(w_o, woT, 1024, 1024);

  gemm_bt_bias<u16><<<dim3(24, 128), 256, 0, stream>>>(
      xb, wqkvT, b_qkv, qkv, 16384, 3072, 1024);
  transpose_v<<<dim3(16, 2, 512), 256, 0, stream>>>(qkv, vtb);
  attn_win<<<dim3(4, 16, 32), 256, 0, stream>>>(qkv, vtb, attnb);
  gemm_bt_bias<float><<<dim3(8, 128), 256, 0, stream>>>(
      attnb, woT, b_o, out, 16384, 1024, 1024);
}

// Round 3
// 606.794 us; speedup vs baseline: 1.1269x; 1.1269x over previous
//
#include <hip/hip_runtime.h>

// Sliding-window attention, MI355X/gfx950. Round 8 (= R7 retry, simplified).
// Pipeline: convert x->bf16, convert+transpose weights -> bf16;
// m97 MFMA GEMM (qkv, bf16 out) -> V transpose -> flash windowed attention
// -> m97 GEMM with FP32 epilogue into d_out. ws usage: 200 MB.
//
// R6 LESSON (reverted): direct-from-global MFMA operands tripled HBM bytes
// (105->278MB fetch) and tanked MfmaUtil 5.2->2.2. Keep cooperative LDS
// staging; win occupancy by SHRINKING LDS instead.
// R7/R8: R5 attn structure with (a) Q hoisted to regs (R6-verified numerics),
// (b) Ps halved to 16KB wave-private reused across two 16-row PV halves
// (WAR safe: same-wave in-order LDS + provable pointer alias keeps program
// order, no inline-asm fences needed), (c) redundant post-P-write barrier
// removed, (d) T14 async-stage: next-tile K/V global loads issued between PV
// halves, LDS write after the post-PV barrier, (e) LDS 48KB -> 3 blocks/CU,
// launch_bounds(256,3). R2 bench was an infra failure; R8 is R7 minus the
// inline-asm fences (semantically identical, less compiler surface).

typedef unsigned short u16;
typedef unsigned int u32;
typedef __attribute__((ext_vector_type(8))) short bf16x8;   // 8 x bf16 (4 VGPRs)
typedef __attribute__((ext_vector_type(4))) float f32x4;

__device__ __forceinline__ float bf2f(u16 v) {
  union { u32 u; float f; } t; t.u = ((u32)v) << 16; return t.f;
}
__device__ __forceinline__ u16 f2bf(float f) {
  union { float f; u32 u; } t; t.f = f;
  u32 u = t.u + 0x7fffu + ((t.u >> 16) & 1u);   // RNE
  return (u16)(u >> 16);
}
__device__ __forceinline__ void g2lds16(const void* g, void* l) {
  __builtin_amdgcn_global_load_lds((const __attribute__((address_space(1))) void*)g,
                                   (__attribute__((address_space(3))) void*)l,
                                   16, 0, 0);
}

// ---------------------------------------------------------------------------
// x [16384][1024] fp32 -> bf16, flat
// ---------------------------------------------------------------------------
__global__ __launch_bounds__(256) void canon_x(
    const float* __restrict__ xf, u16* __restrict__ xb) {
  size_t i = ((size_t)blockIdx.x * 256 + threadIdx.x) * 8;
  float4 a = *(const float4*)(xf + i);
  float4 b = *(const float4*)(xf + i + 4);
  u16 o[8] = { f2bf(a.x), f2bf(a.y), f2bf(a.z), f2bf(a.w),
               f2bf(b.x), f2bf(b.y), f2bf(b.z), f2bf(b.w) };
  *(bf16x8*)(xb + i) = *(bf16x8*)o;
}

// ---------------------------------------------------------------------------
// Weight transpose+convert: in [R][C] fp32 -> out [C][R] bf16
// ---------------------------------------------------------------------------
__global__ __launch_bounds__(256) void transpose_w(
    const float* __restrict__ in, u16* __restrict__ out, int R, int C) {
  __shared__ u16 tile[32][33];
  int c0 = blockIdx.x * 32, r0 = blockIdx.y * 32;
  int tx = threadIdx.x & 31, ty = threadIdx.x >> 5;
#pragma unroll
  for (int i = 0; i < 32; i += 8)
    tile[ty + i][tx] = f2bf(in[(size_t)(r0 + ty + i) * C + c0 + tx]);
  __syncthreads();
#pragma unroll
  for (int i = 0; i < 32; i += 8)
    out[(size_t)(c0 + ty + i) * R + r0 + tx] = tile[tx][ty + i];
}

// ---------------------------------------------------------------------------
// V part of qkv [16384][3072] -> Vt [bh=512][d=64][t=512]   (bf16)
// ---------------------------------------------------------------------------
__global__ __launch_bounds__(256) void transpose_v(
    const u16* __restrict__ qkv, u16* __restrict__ vt) {
  __shared__ u16 tile[32][33];
  int bh = blockIdx.z, bn = bh >> 4, h = bh & 15;
  int t0 = blockIdx.x * 32, d0 = blockIdx.y * 32;
  int tx = threadIdx.x & 31, ty = threadIdx.x >> 5;
  const u16* src = qkv + (size_t)(bn * 512) * 3072 + 2048 + h * 64;
#pragma unroll
  for (int i = 0; i < 32; i += 8)
    tile[ty + i][tx] = src[(size_t)(t0 + ty + i) * 3072 + d0 + tx];
  __syncthreads();
  u16* dst = vt + ((size_t)bh * 64 + d0) * 512 + t0;
#pragma unroll
  for (int i = 0; i < 32; i += 8)
    dst[(size_t)(ty + i) * 512 + tx] = tile[tx][ty + i];
}

// ---------------------------------------------------------------------------
// C[M,N] = A[M,K](bf16) * Bt[N,K]^T(bf16) + bias[N](fp32); OutT u16|float.
// m97 structure: 128x128 tile, BK=32, 2x2 waves of 64x64, global_load_lds w=16.
// ---------------------------------------------------------------------------
template <typename OutT>
__global__ __launch_bounds__(256, 2) void gemm_bt_bias(
    const u16* __restrict__ A, const u16* __restrict__ Bt,
    const float* __restrict__ bias, OutT* __restrict__ C,
    int M, int N, int K) {
  __shared__ __align__(16) u16 As[128 * 32];
  __shared__ __align__(16) u16 Bs[128 * 32];
  const int tid = threadIdx.x;
  const int wave = tid >> 6, lane = tid & 63;
  const int quad = lane >> 4, l16 = lane & 15;
  const int m0 = blockIdx.y * 128, n0 = blockIdx.x * 128;
  const int wm = (wave >> 1) * 64, wn = (wave & 1) * 64;

  f32x4 acc[4][4] = {};

  int e0 = (wave * 512) + lane * 8;   // chunk 0 element offset in 128x32 tile
  int e1 = 2048 + e0;                 // chunk 1
  int rA0 = e0 >> 5, cA0 = e0 & 31;
  int rA1 = e1 >> 5, cA1 = e1 & 31;
  const u16* ga0 = A + (size_t)(m0 + rA0) * K + cA0;
  const u16* ga1 = A + (size_t)(m0 + rA1) * K + cA1;
  const u16* gb0 = Bt + (size_t)(n0 + rA0) * K + cA0;
  const u16* gb1 = Bt + (size_t)(n0 + rA1) * K + cA1;
  u16* As0 = As + (size_t)wave * 512;
  u16* As1 = As0 + 2048;
  u16* Bs0 = Bs + (size_t)wave * 512;
  u16* Bs1 = Bs0 + 2048;

  for (int k0 = 0; k0 < K; k0 += 32) {
    g2lds16(ga0 + k0, As0);
    g2lds16(ga1 + k0, As1);
    g2lds16(gb0 + k0, Bs0);
    g2lds16(gb1 + k0, Bs1);
    __syncthreads();
    bf16x8 a[4], b[4];
#pragma unroll
    for (int mi = 0; mi < 4; ++mi)
      a[mi] = *(const bf16x8*)(As + (wm + mi * 16 + l16) * 32 + quad * 8);
#pragma unroll
    for (int ni = 0; ni < 4; ++ni)
      b[ni] = *(const bf16x8*)(Bs + (wn + ni * 16 + l16) * 32 + quad * 8);
#pragma unroll
    for (int mi = 0; mi < 4; ++mi)
#pragma unroll
      for (int ni = 0; ni < 4; ++ni)
        acc[mi][ni] = __builtin_amdgcn_mfma_f32_16x16x32_bf16(a[mi], b[ni], acc[mi][ni], 0, 0, 0);
    __syncthreads();
  }

  // epilogue: C/D layout col=l16, row=quad*4+reg
#pragma unroll
  for (int ni = 0; ni < 4; ++ni) {
    int col = n0 + wn + ni * 16 + l16;
    float bv = bias[col];
#pragma unroll
    for (int mi = 0; mi < 4; ++mi) {
      int row = m0 + wm + mi * 16 + quad * 4;
#pragma unroll
      for (int r = 0; r < 4; ++r) {
        float v = acc[mi][ni][r] + bv;
        if constexpr (sizeof(OutT) == 2)
          C[(size_t)(row + r) * N + col] = f2bf(v);
        else
          C[(size_t)(row + r) * N + col] = v;
      }
    }
  }
}

// ---------------------------------------------------------------------------
// Windowed causal flash attention. Grid (qt=4, h=16, bn=32), 256 threads.
// R8: R5 staged structure; Q in regs; Ks/Vs staged in swizzled LDS;
// Ps = one 16x128 wave-private buffer reused by both PV halves;
// barriers only around the Ks/Vs overwrite (skipped on last tile);
// T14: next-tile K/V loads issued between PV halves, LDS write after barrier.
// LDS 48KB -> 3 blocks/CU.
// ---------------------------------------------------------------------------
__global__ __launch_bounds__(256, 3) void attn_win(
    const u16* __restrict__ qkv, const u16* __restrict__ vt,
    u16* __restrict__ attn) {
  __shared__ __align__(16) u16 Ks[128 * 64];
  __shared__ __align__(16) u16 Vs[64 * 128];
  __shared__ __align__(16) u16 Ps[4][16 * 128];

  const int qt = blockIdx.x, h = blockIdx.y, bn = blockIdx.z;
  const int bh = bn * 16 + h;
  const int tid = threadIdx.x;
  const int wave = tid >> 6, lane = tid & 63;
  const int quad = lane >> 4, l16 = lane & 15;
  const int t0 = bn * 512 + qt * 128;

  // ---- Q operand fragments in registers (R6-verified layout) ----
  bf16x8 aq[2][2];
#pragma unroll
  for (int mi = 0; mi < 2; ++mi)
#pragma unroll
    for (int ks = 0; ks < 2; ++ks)
      aq[mi][ks] = *(const bf16x8*)(
          qkv + (size_t)(t0 + wave * 32 + mi * 16 + l16) * 3072 + h * 64 + ks * 32 + quad * 8);

  // ---- prologue: stage K/V tile j=0 into swizzled LDS (coalesced) ----
  {
    const int tk = bn * 512;
#pragma unroll
    for (int it = 0; it < 4; ++it) {
      int i = it * 256 + tid;
      int rk = i >> 3, ck = i & 7;
      bf16x8 kv = *(const bf16x8*)(qkv + (size_t)(tk + rk) * 3072 + 1024 + h * 64 + ck * 8);
      *(bf16x8*)(Ks + rk * 64 + ((ck ^ (rk & 7)) * 8)) = kv;
      int rv = i >> 4, cv = i & 15;
      bf16x8 vv = *(const bf16x8*)(vt + ((size_t)bh * 64 + rv) * 512 + cv * 8);
      *(bf16x8*)(Vs + rv * 128 + ((cv ^ (rv & 15)) * 8)) = vv;
    }
  }
  __syncthreads();

  float mrun[2][4], lrun[2][4];
  f32x4 o[2][4] = {};
#pragma unroll
  for (int mi = 0; mi < 2; ++mi)
#pragma unroll
    for (int r = 0; r < 4; ++r) { mrun[mi][r] = -1e30f; lrun[mi][r] = 0.f; }

  const float cexp = 0.18033688011112042f;  // (1/sqrt(64)) * log2(e)

  bf16x8 kreg[4], vreg[4];                 // T14 staging registers
  u16* pw = &Ps[wave][0];

  for (int j = 0; j <= qt; ++j) {
    // ---- S = Q K^T (this wave: rows [wave*32, +32)) ----
    f32x4 s[2][8] = {};
    __builtin_amdgcn_s_setprio(1);
#pragma unroll
    for (int ks = 0; ks < 2; ++ks) {
#pragma unroll
      for (int ni = 0; ni < 8; ++ni) {
        int n = ni * 16 + l16;
        bf16x8 bk = *(const bf16x8*)(Ks + n * 64 + (((ks * 4 + quad) ^ (n & 7)) * 8));
        s[0][ni] = __builtin_amdgcn_mfma_f32_16x16x32_bf16(aq[0][ks], bk, s[0][ni], 0, 0, 0);
        s[1][ni] = __builtin_amdgcn_mfma_f32_16x16x32_bf16(aq[1][ks], bk, s[1][ni], 0, 0, 0);
      }
    }
    __builtin_amdgcn_s_setprio(0);

    // ---- online softmax (C layout: col=l16, row=quad*4+r) ----
    const bool diag = (j == qt);
#pragma unroll
    for (int mi = 0; mi < 2; ++mi) {
#pragma unroll
      for (int r = 0; r < 4; ++r) {
        int m = wave * 32 + mi * 16 + quad * 4 + r;
        float rmax = -1e30f;
#pragma unroll
        for (int ni = 0; ni < 8; ++ni) {
          float v = s[mi][ni][r] * cexp;
          if (diag && (ni * 16 + l16 > m)) v = -1e30f;
          s[mi][ni][r] = v;
          rmax = fmaxf(rmax, v);
        }
        rmax = fmaxf(rmax, __shfl_xor(rmax, 1));
        rmax = fmaxf(rmax, __shfl_xor(rmax, 2));
        rmax = fmaxf(rmax, __shfl_xor(rmax, 4));
        rmax = fmaxf(rmax, __shfl_xor(rmax, 8));
        float mnew = fmaxf(mrun[mi][r], rmax);
        float alpha = exp2f(mrun[mi][r] - mnew);
        mrun[mi][r] = mnew;
        float rsum = 0.f;
#pragma unroll
        for (int ni = 0; ni < 8; ++ni) {
          float pv = exp2f(s[mi][ni][r] - mnew);
          s[mi][ni][r] = pv;
          rsum += pv;
        }
        rsum += __shfl_xor(rsum, 1);
        rsum += __shfl_xor(rsum, 2);
        rsum += __shfl_xor(rsum, 4);
        rsum += __shfl_xor(rsum, 8);
        lrun[mi][r] = lrun[mi][r] * alpha + rsum;
#pragma unroll
        for (int di = 0; di < 4; ++di) o[mi][di][r] *= alpha;
      }
    }

    // ---- half 0: P-write (wave-private, no barrier) then PV ----
    // WAR/RAW on pw is same-wave through one aliasing pointer: program
    // order is preserved by the compiler and the in-order LDS pipe.
#pragma unroll
    for (int ni = 0; ni < 8; ++ni)
#pragma unroll
      for (int r = 0; r < 4; ++r) {
        int row = quad * 4 + r;               // 0..15 within this half
        int col = ni * 16 + l16;
        int phys = (col >> 3) ^ row;
        pw[row * 128 + phys * 8 + (col & 7)] = f2bf(s[0][ni][r]);
      }

    __builtin_amdgcn_s_setprio(1);
#pragma unroll
    for (int ksv = 0; ksv < 4; ++ksv) {
      bf16x8 ap = *(const bf16x8*)(pw + l16 * 128 + (((ksv * 4 + quad) ^ l16) * 8));
#pragma unroll
      for (int di = 0; di < 4; ++di) {
        int n = di * 16 + l16;
        bf16x8 bv = *(const bf16x8*)(Vs + n * 128 + (((ksv * 4 + quad) ^ (n & 15)) * 8));
        o[0][di] = __builtin_amdgcn_mfma_f32_16x16x32_bf16(ap, bv, o[0][di], 0, 0, 0);
      }
    }
    __builtin_amdgcn_s_setprio(0);

    // ---- T14: issue next-tile staging loads (global -> regs); s[0] dead ----
    if (j < qt) {
      const int tk1 = bn * 512 + (j + 1) * 128;
#pragma unroll
      for (int it = 0; it < 4; ++it) {
        int i = it * 256 + tid;
        int rk = i >> 3, ck = i & 7;
        kreg[it] = *(const bf16x8*)(
            qkv + (size_t)(tk1 + rk) * 3072 + 1024 + h * 64 + ck * 8);
        int rv = i >> 4, cv = i & 15;
        vreg[it] = *(const bf16x8*)(
            vt + ((size_t)bh * 64 + rv) * 512 + (j + 1) * 128 + cv * 8);
      }
    }

    // ---- half 1: P-write then PV ----
#pragma unroll
    for (int ni = 0; ni < 8; ++ni)
#pragma unroll
      for (int r = 0; r < 4; ++r) {
        int row = quad * 4 + r;
        int col = ni * 16 + l16;
        int phys = (col >> 3) ^ row;
        pw[row * 128 + phys * 8 + (col & 7)] = f2bf(s[1][ni][r]);
      }

    __builtin_amdgcn_s_setprio(1);
#pragma unroll
    for (int ksv = 0; ksv < 4; ++ksv) {
      bf16x8 ap = *(const bf16x8*)(pw + l16 * 128 + (((ksv * 4 + quad) ^ l16) * 8));
#pragma unroll
      for (int di = 0; di < 4; ++di) {
        int n = di * 16 + l16;
        bf16x8 bv = *(const bf16x8*)(Vs + n * 128 + (((ksv * 4 + quad) ^ (n & 15)) * 8));
        o[1][di] = __builtin_amdgcn_mfma_f32_16x16x32_bf16(ap, bv, o[1][di], 0, 0, 0);
      }
    }
    __builtin_amdgcn_s_setprio(0);

    if (j < qt) {
      __syncthreads();     // all waves done reading Ks/Vs
      // ---- write staged regs -> LDS (compiler inserts vmcnt wait) ----
#pragma unroll
      for (int it = 0; it < 4; ++it) {
        int i = it * 256 + tid;
        int rk = i >> 3, ck = i & 7;
        *(bf16x8*)(Ks + rk * 64 + ((ck ^ (rk & 7)) * 8)) = kreg[it];
        int rv = i >> 4, cv = i & 15;
        *(bf16x8*)(Vs + rv * 128 + ((cv ^ (rv & 15)) * 8)) = vreg[it];
      }
      __syncthreads();     // writes visible to all waves
    }
  }

  // ---- epilogue: O / l -> attn [token][h*64+d] (bf16) ----
#pragma unroll
  for (int mi = 0; mi < 2; ++mi)
#pragma unroll
    for (int r = 0; r < 4; ++r) {
      float inv = 1.0f / lrun[mi][r];
      int trow = t0 + wave * 32 + mi * 16 + quad * 4 + r;
#pragma unroll
      for (int di = 0; di < 4; ++di)
        attn[(size_t)trow * 1024 + h * 64 + di * 16 + l16] = f2bf(o[mi][di][r] * inv);
    }
}

// ---------------------------------------------------------------------------
extern "C" void kernel_launch(void* const* d_in, const int* in_sizes, int n_in,
                              void* d_out, int out_size, void* d_ws, size_t ws_size,
                              hipStream_t stream) {
  (void)in_sizes; (void)n_in; (void)out_size; (void)ws_size;
  const float* x     = (const float*)d_in[0];   // [16384][1024] fp32
  const float* w_qkv = (const float*)d_in[1];   // [1024][3072] fp32
  const float* b_qkv = (const float*)d_in[2];   // [3072] fp32
  const float* w_o   = (const float*)d_in[3];   // [1024][1024] fp32
  const float* b_o   = (const float*)d_in[4];   // [1024] fp32
  float* out = (float*)d_out;                   // [16384][1024] fp32

  char* ws = (char*)d_ws;
  u16* qkv   = (u16*)(ws + 0);            // 96 MB
  u16* vtb   = (u16*)(ws + 100663296);    // 32 MB
  u16* attnb = (u16*)(ws + 134217728);    // 32 MB
  u16* xb    = (u16*)(ws + 167772160);    // 32 MB
  u16* wqkvT = (u16*)(ws + 201326592);    // 6 MB
  u16* woT   = (u16*)(ws + 207618048);    // 2 MB  (total 200 MB)

  canon_x<<<8192, 256, 0, stream>>>(x, xb);
  transpose_w<<<dim3(96, 32), 256, 0, stream>>>(w_qkv, wqkvT, 1024, 3072);
  transpose_w<<<dim3(32, 32), 256, 0, stream>>>(w_o, woT, 1024, 1024);

  gemm_bt_bias<u16><<<dim3(24, 128), 256, 0, stream>>>(
      xb, wqkvT, b_qkv, qkv, 16384, 3072, 1024);
  transpose_v<<<dim3(16, 2, 512), 256, 0, stream>>>(qkv, vtb);
  attn_win<<<dim3(4, 16, 32), 256, 0, stream>>>(qkv, vtb, attnb);
  gemm_bt_bias<float><<<dim3(8, 128), 256, 0, stream>>>(
      attnb, woT, b_o, out, 16384, 1024, 1024);
}

// Round 4
// 434.891 us; speedup vs baseline: 1.5724x; 1.3953x over previous
//
#include <hip/hip_runtime.h>

// Sliding-window attention, MI355X/gfx950. Round 9.
// Pipeline: convert x->bf16, convert+transpose weights -> bf16;
// m97 MFMA GEMM (qkv, bf16 out) -> V transpose -> flash windowed attention
// -> m97 GEMM with FP32 epilogue into d_out. ws usage: 200 MB.
//
// R6 LESSON: don't feed MFMA straight from global (FETCH 3x).
// R8 LESSON: __launch_bounds__(256,3) + reg-staged K/V => compiler demoted
// arrays to scratch (VGPR 84, WRITE 416MB). Fix: (256,2) so no forced cap,
// and stage K/V via global_load_lds with PRE-SWIZZLED per-lane SOURCE
// addresses (m173): LDS dest stays linear (wave-uniform base + lane*16),
// the XOR involution moves to the global address, readers unchanged.
// Ps stays halved (16KB wave-private, both PV halves) - numerics verified R8.
// LDS 48KB -> 3 blocks/CU when VGPR <= 170.

typedef unsigned short u16;
typedef unsigned int u32;
typedef __attribute__((ext_vector_type(8))) short bf16x8;   // 8 x bf16 (4 VGPRs)
typedef __attribute__((ext_vector_type(4))) float f32x4;

__device__ __forceinline__ float bf2f(u16 v) {
  union { u32 u; float f; } t; t.u = ((u32)v) << 16; return t.f;
}
__device__ __forceinline__ u16 f2bf(float f) {
  union { float f; u32 u; } t; t.f = f;
  u32 u = t.u + 0x7fffu + ((t.u >> 16) & 1u);   // RNE
  return (u16)(u >> 16);
}
__device__ __forceinline__ void g2lds16(const void* g, void* l) {
  __builtin_amdgcn_global_load_lds((const __attribute__((address_space(1))) void*)g,
                                   (__attribute__((address_space(3))) void*)l,
                                   16, 0, 0);
}

// ---------------------------------------------------------------------------
// x [16384][1024] fp32 -> bf16, flat
// ---------------------------------------------------------------------------
__global__ __launch_bounds__(256) void canon_x(
    const float* __restrict__ xf, u16* __restrict__ xb) {
  size_t i = ((size_t)blockIdx.x * 256 + threadIdx.x) * 8;
  float4 a = *(const float4*)(xf + i);
  float4 b = *(const float4*)(xf + i + 4);
  u16 o[8] = { f2bf(a.x), f2bf(a.y), f2bf(a.z), f2bf(a.w),
               f2bf(b.x), f2bf(b.y), f2bf(b.z), f2bf(b.w) };
  *(bf16x8*)(xb + i) = *(bf16x8*)o;
}

// ---------------------------------------------------------------------------
// Weight transpose+convert: in [R][C] fp32 -> out [C][R] bf16
// ---------------------------------------------------------------------------
__global__ __launch_bounds__(256) void transpose_w(
    const float* __restrict__ in, u16* __restrict__ out, int R, int C) {
  __shared__ u16 tile[32][33];
  int c0 = blockIdx.x * 32, r0 = blockIdx.y * 32;
  int tx = threadIdx.x & 31, ty = threadIdx.x >> 5;
#pragma unroll
  for (int i = 0; i < 32; i += 8)
    tile[ty + i][tx] = f2bf(in[(size_t)(r0 + ty + i) * C + c0 + tx]);
  __syncthreads();
#pragma unroll
  for (int i = 0; i < 32; i += 8)
    out[(size_t)(c0 + ty + i) * R + r0 + tx] = tile[tx][ty + i];
}

// ---------------------------------------------------------------------------
// V part of qkv [16384][3072] -> Vt [bh=512][d=64][t=512]   (bf16)
// ---------------------------------------------------------------------------
__global__ __launch_bounds__(256) void transpose_v(
    const u16* __restrict__ qkv, u16* __restrict__ vt) {
  __shared__ u16 tile[32][33];
  int bh = blockIdx.z, bn = bh >> 4, h = bh & 15;
  int t0 = blockIdx.x * 32, d0 = blockIdx.y * 32;
  int tx = threadIdx.x & 31, ty = threadIdx.x >> 5;
  const u16* src = qkv + (size_t)(bn * 512) * 3072 + 2048 + h * 64;
#pragma unroll
  for (int i = 0; i < 32; i += 8)
    tile[ty + i][tx] = src[(size_t)(t0 + ty + i) * 3072 + d0 + tx];
  __syncthreads();
  u16* dst = vt + ((size_t)bh * 64 + d0) * 512 + t0;
#pragma unroll
  for (int i = 0; i < 32; i += 8)
    dst[(size_t)(ty + i) * 512 + tx] = tile[tx][ty + i];
}

// ---------------------------------------------------------------------------
// C[M,N] = A[M,K](bf16) * Bt[N,K]^T(bf16) + bias[N](fp32); OutT u16|float.
// m97 structure: 128x128 tile, BK=32, 2x2 waves of 64x64, global_load_lds w=16.
// ---------------------------------------------------------------------------
template <typename OutT>
__global__ __launch_bounds__(256, 2) void gemm_bt_bias(
    const u16* __restrict__ A, const u16* __restrict__ Bt,
    const float* __restrict__ bias, OutT* __restrict__ C,
    int M, int N, int K) {
  __shared__ __align__(16) u16 As[128 * 32];
  __shared__ __align__(16) u16 Bs[128 * 32];
  const int tid = threadIdx.x;
  const int wave = tid >> 6, lane = tid & 63;
  const int quad = lane >> 4, l16 = lane & 15;
  const int m0 = blockIdx.y * 128, n0 = blockIdx.x * 128;
  const int wm = (wave >> 1) * 64, wn = (wave & 1) * 64;

  f32x4 acc[4][4] = {};

  int e0 = (wave * 512) + lane * 8;   // chunk 0 element offset in 128x32 tile
  int e1 = 2048 + e0;                 // chunk 1
  int rA0 = e0 >> 5, cA0 = e0 & 31;
  int rA1 = e1 >> 5, cA1 = e1 & 31;
  const u16* ga0 = A + (size_t)(m0 + rA0) * K + cA0;
  const u16* ga1 = A + (size_t)(m0 + rA1) * K + cA1;
  const u16* gb0 = Bt + (size_t)(n0 + rA0) * K + cA0;
  const u16* gb1 = Bt + (size_t)(n0 + rA1) * K + cA1;
  u16* As0 = As + (size_t)wave * 512;
  u16* As1 = As0 + 2048;
  u16* Bs0 = Bs + (size_t)wave * 512;
  u16* Bs1 = Bs0 + 2048;

  for (int k0 = 0; k0 < K; k0 += 32) {
    g2lds16(ga0 + k0, As0);
    g2lds16(ga1 + k0, As1);
    g2lds16(gb0 + k0, Bs0);
    g2lds16(gb1 + k0, Bs1);
    __syncthreads();
    bf16x8 a[4], b[4];
#pragma unroll
    for (int mi = 0; mi < 4; ++mi)
      a[mi] = *(const bf16x8*)(As + (wm + mi * 16 + l16) * 32 + quad * 8);
#pragma unroll
    for (int ni = 0; ni < 4; ++ni)
      b[ni] = *(const bf16x8*)(Bs + (wn + ni * 16 + l16) * 32 + quad * 8);
#pragma unroll
    for (int mi = 0; mi < 4; ++mi)
#pragma unroll
      for (int ni = 0; ni < 4; ++ni)
        acc[mi][ni] = __builtin_amdgcn_mfma_f32_16x16x32_bf16(a[mi], b[ni], acc[mi][ni], 0, 0, 0);
    __syncthreads();
  }

  // epilogue: C/D layout col=l16, row=quad*4+reg
#pragma unroll
  for (int ni = 0; ni < 4; ++ni) {
    int col = n0 + wn + ni * 16 + l16;
    float bv = bias[col];
#pragma unroll
    for (int mi = 0; mi < 4; ++mi) {
      int row = m0 + wm + mi * 16 + quad * 4;
#pragma unroll
      for (int r = 0; r < 4; ++r) {
        float v = acc[mi][ni][r] + bv;
        if constexpr (sizeof(OutT) == 2)
          C[(size_t)(row + r) * N + col] = f2bf(v);
        else
          C[(size_t)(row + r) * N + col] = v;
      }
    }
  }
}

// ---------------------------------------------------------------------------
// Windowed causal flash attention. Grid (qt=4, h=16, bn=32), 256 threads.
// R9: Q in regs; K/V staged via global_load_lds w=16 with pre-swizzled
// SOURCE addresses (LDS linear dest; swizzle relation identical to R5/R8
// readers: LDS[row][phys_chunk] = logical chunk phys^(row&mask)).
// Ps = one 16x128 wave-private buffer reused by both PV halves (R8-verified).
// Two barriers per K/V tile (drain + publish), none on the last tile.
// LDS 48KB; launch_bounds(256,2) so the compiler is NOT forced to spill.
// ---------------------------------------------------------------------------
__global__ __launch_bounds__(256, 2) void attn_win(
    const u16* __restrict__ qkv, const u16* __restrict__ vt,
    u16* __restrict__ attn) {
  __shared__ __align__(16) u16 Ks[128 * 64];
  __shared__ __align__(16) u16 Vs[64 * 128];
  __shared__ __align__(16) u16 Ps[4][16 * 128];

  const int qt = blockIdx.x, h = blockIdx.y, bn = blockIdx.z;
  const int bh = bn * 16 + h;
  const int tid = threadIdx.x;
  const int wave = tid >> 6, lane = tid & 63;
  const int quad = lane >> 4, l16 = lane & 15;
  const int t0 = bn * 512 + qt * 128;

  // ---- Q operand fragments in registers (R6-verified layout) ----
  bf16x8 aq[2][2];
#pragma unroll
  for (int mi = 0; mi < 2; ++mi)
#pragma unroll
    for (int ks = 0; ks < 2; ++ks)
      aq[mi][ks] = *(const bf16x8*)(
          qkv + (size_t)(t0 + wave * 32 + mi * 16 + l16) * 3072 + h * 64 + ks * 32 + quad * 8);

  // ---- K/V staging via global_load_lds, pre-swizzled source (m173) ----
  // K: chunk i (16B) of the 128x64 tile: rk=i>>3 (row), ck=i&7 (phys slot);
  //    source = logical chunk ck^(rk&7)  -> LDS[rk][phys=ck] = K[rk][ck^(rk&7)]
  // V: chunk i of the 64x128 tile: rv=i>>4, cv=i&15; source chunk cv^(rv&15).
  // Readers (below) use the same XOR involution as R5/R8 - unchanged.
  // LDS dest is wave-uniform: chunk base it*256 + wave*64, lane adds l*16B.
  const int iK = tid;                       // chunk index base (per it: +256)
  const int rk0 = iK >> 3, ck0 = iK & 7;
  const int rv0 = iK >> 4, cv0 = iK & 15;

#define STAGE_KV(JT)                                                          \
  {                                                                           \
    const int tk_ = bn * 512 + (JT) * 128;                                    \
    _Pragma("unroll")                                                         \
    for (int it = 0; it < 4; ++it) {                                          \
      int rk = it * 32 + rk0;              /* +256 chunks = +32 K rows */     \
      const u16* gk = qkv + (size_t)(tk_ + rk) * 3072 + 1024 + h * 64 +       \
                      ((ck0 ^ (rk & 7)) * 8);                                 \
      g2lds16(gk, Ks + (size_t)(it * 256 + wave * 64) * 8);                   \
      int rv = it * 16 + rv0;              /* +256 chunks = +16 V rows */     \
      const u16* gv = vt + ((size_t)bh * 64 + rv) * 512 + (JT) * 128 +        \
                      ((cv0 ^ (rv & 15)) * 8);                                \
      g2lds16(gv, Vs + (size_t)(it * 256 + wave * 64) * 8);                   \
    }                                                                         \
  }

  STAGE_KV(0);
  __syncthreads();

  float mrun[2][4], lrun[2][4];
  f32x4 o[2][4] = {};
#pragma unroll
  for (int mi = 0; mi < 2; ++mi)
#pragma unroll
    for (int r = 0; r < 4; ++r) { mrun[mi][r] = -1e30f; lrun[mi][r] = 0.f; }

  const float cexp = 0.18033688011112042f;  // (1/sqrt(64)) * log2(e)

  u16* pw = &Ps[wave][0];

  for (int j = 0; j <= qt; ++j) {
    // ---- S = Q K^T (this wave: rows [wave*32, +32)) ----
    f32x4 s[2][8] = {};
    __builtin_amdgcn_s_setprio(1);
#pragma unroll
    for (int ks = 0; ks < 2; ++ks) {
#pragma unroll
      for (int ni = 0; ni < 8; ++ni) {
        int n = ni * 16 + l16;
        bf16x8 bk = *(const bf16x8*)(Ks + n * 64 + (((ks * 4 + quad) ^ (n & 7)) * 8));
        s[0][ni] = __builtin_amdgcn_mfma_f32_16x16x32_bf16(aq[0][ks], bk, s[0][ni], 0, 0, 0);
        s[1][ni] = __builtin_amdgcn_mfma_f32_16x16x32_bf16(aq[1][ks], bk, s[1][ni], 0, 0, 0);
      }
    }
    __builtin_amdgcn_s_setprio(0);

    // ---- online softmax (C layout: col=l16, row=quad*4+r) ----
    const bool diag = (j == qt);
#pragma unroll
    for (int mi = 0; mi < 2; ++mi) {
#pragma unroll
      for (int r = 0; r < 4; ++r) {
        int m = wave * 32 + mi * 16 + quad * 4 + r;
        float rmax = -1e30f;
#pragma unroll
        for (int ni = 0; ni < 8; ++ni) {
          float v = s[mi][ni][r] * cexp;
          if (diag && (ni * 16 + l16 > m)) v = -1e30f;
          s[mi][ni][r] = v;
          rmax = fmaxf(rmax, v);
        }
        rmax = fmaxf(rmax, __shfl_xor(rmax, 1));
        rmax = fmaxf(rmax, __shfl_xor(rmax, 2));
        rmax = fmaxf(rmax, __shfl_xor(rmax, 4));
        rmax = fmaxf(rmax, __shfl_xor(rmax, 8));
        float mnew = fmaxf(mrun[mi][r], rmax);
        float alpha = exp2f(mrun[mi][r] - mnew);
        mrun[mi][r] = mnew;
        float rsum = 0.f;
#pragma unroll
        for (int ni = 0; ni < 8; ++ni) {
          float pv = exp2f(s[mi][ni][r] - mnew);
          s[mi][ni][r] = pv;
          rsum += pv;
        }
        rsum += __shfl_xor(rsum, 1);
        rsum += __shfl_xor(rsum, 2);
        rsum += __shfl_xor(rsum, 4);
        rsum += __shfl_xor(rsum, 8);
        lrun[mi][r] = lrun[mi][r] * alpha + rsum;
#pragma unroll
        for (int di = 0; di < 4; ++di) o[mi][di][r] *= alpha;
      }
    }

    // ---- two 16-row halves: P-write (wave-private, no barrier) then PV ----
    // WAR/RAW on pw is same-wave through one aliasing pointer: program
    // order is preserved by the compiler and the in-order LDS pipe.
#pragma unroll
    for (int mi = 0; mi < 2; ++mi) {
#pragma unroll
      for (int ni = 0; ni < 8; ++ni)
#pragma unroll
        for (int r = 0; r < 4; ++r) {
          int row = quad * 4 + r;               // 0..15 within this half
          int col = ni * 16 + l16;
          int phys = (col >> 3) ^ row;
          pw[row * 128 + phys * 8 + (col & 7)] = f2bf(s[mi][ni][r]);
        }

      __builtin_amdgcn_s_setprio(1);
#pragma unroll
      for (int ksv = 0; ksv < 4; ++ksv) {
        bf16x8 ap = *(const bf16x8*)(pw + l16 * 128 + (((ksv * 4 + quad) ^ l16) * 8));
#pragma unroll
        for (int di = 0; di < 4; ++di) {
          int n = di * 16 + l16;
          bf16x8 bv = *(const bf16x8*)(Vs + n * 128 + (((ksv * 4 + quad) ^ (n & 15)) * 8));
          o[mi][di] = __builtin_amdgcn_mfma_f32_16x16x32_bf16(ap, bv, o[mi][di], 0, 0, 0);
        }
      }
      __builtin_amdgcn_s_setprio(0);
    }

    if (j < qt) {
      __syncthreads();        // all waves done reading Ks/Vs
      STAGE_KV(j + 1);        // DMA refill (linear dest, swizzled source)
      __syncthreads();        // vmcnt drained by barrier; tile published
    }
  }
#undef STAGE_KV

  // ---- epilogue: O / l -> attn [token][h*64+d] (bf16) ----
#pragma unroll
  for (int mi = 0; mi < 2; ++mi)
#pragma unroll
    for (int r = 0; r < 4; ++r) {
      float inv = 1.0f / lrun[mi][r];
      int trow = t0 + wave * 32 + mi * 16 + quad * 4 + r;
#pragma unroll
      for (int di = 0; di < 4; ++di)
        attn[(size_t)trow * 1024 + h * 64 + di * 16 + l16] = f2bf(o[mi][di][r] * inv);
    }
}

// ---------------------------------------------------------------------------
extern "C" void kernel_launch(void* const* d_in, const int* in_sizes, int n_in,
                              void* d_out, int out_size, void* d_ws, size_t ws_size,
                              hipStream_t stream) {
  (void)in_sizes; (void)n_in; (void)out_size; (void)ws_size;
  const float* x     = (const float*)d_in[0];   // [16384][1024] fp32
  const float* w_qkv = (const float*)d_in[1];   // [1024][3072] fp32
  const float* b_qkv = (const float*)d_in[2];   // [3072] fp32
  const float* w_o   = (const float*)d_in[3];   // [1024][1024] fp32
  const float* b_o   = (const float*)d_in[4];   // [1024] fp32
  float* out = (float*)d_out;                   // [16384][1024] fp32

  char* ws = (char*)d_ws;
  u16* qkv   = (u16*)(ws + 0);            // 96 MB
  u16* vtb   = (u16*)(ws + 100663296);    // 32 MB
  u16* attnb = (u16*)(ws + 134217728);    // 32 MB
  u16* xb    = (u16*)(ws + 167772160);    // 32 MB
  u16* wqkvT = (u16*)(ws + 201326592);    // 6 MB
  u16* woT   = (u16*)(ws + 207618048);    // 2 MB  (total 200 MB)

  canon_x<<<8192, 256, 0, stream>>>(x, xb);
  transpose_w<<<dim3(96, 32), 256, 0, stream>>>(w_qkv, wqkvT, 1024, 3072);
  transpose_w<<<dim3(32, 32), 256, 0, stream>>>(w_o, woT, 1024, 1024);

  gemm_bt_bias<u16><<<dim3(24, 128), 256, 0, stream>>>(
      xb, wqkvT, b_qkv, qkv, 16384, 3072, 1024);
  transpose_v<<<dim3(16, 2, 512), 256, 0, stream>>>(qkv, vtb);
  attn_win<<<dim3(4, 16, 32), 256, 0, stream>>>(qkv, vtb, attnb);
  gemm_bt_bias<float><<<dim3(8, 128), 256, 0, stream>>>(
      attnb, woT, b_o, out, 16384, 1024, 1024);
}

// Round 5
// 427.785 us; speedup vs baseline: 1.5985x; 1.0166x over previous
//
#include <hip/hip_runtime.h>

// Sliding-window attention, MI355X/gfx950. Round 10.
// Pipeline: convert x->bf16, convert+transpose weights -> bf16;
// m97 MFMA GEMM (qkv, bf16 out) -> V transpose -> flash windowed attention
// -> m97 GEMM with FP32 epilogue into d_out. ws usage: 200 MB.
//
// R6 LESSON: don't feed MFMA straight from global (FETCH 3x).
// R8 LESSON: forced waves/EU bound => scratch spill (VGPR 84, WRITE 416MB).
// R9 (verified, 150us attn): gload_lds w=16 with pre-swizzled SOURCE, linear
// LDS dest; no spill; 3 blocks/CU. Remaining stall: __syncthreads forces
// s_waitcnt vmcnt(0) immediately after the DMA issue -> full latency exposed.
// R10: counted-vmcnt pipeline with RAW s_barrier (T3/T4). Per tile:
//   QK -> barA -> issue K(j+1) -> softmax -> vmcnt(4) barD -> P+PV
//      -> vmcnt(0) barB -> issue V(j+1)
// K DMA hides under softmax+PV; V DMA hides under next QK+softmax.
// No __syncthreads in the loop => no forced drains. VGPR unchanged.
// Also: T1 XCD-aware block swizzle on both GEMMs (nwg%8==0, bijective).

typedef unsigned short u16;
typedef unsigned int u32;
typedef __attribute__((ext_vector_type(8))) short bf16x8;   // 8 x bf16 (4 VGPRs)
typedef __attribute__((ext_vector_type(4))) float f32x4;

__device__ __forceinline__ float bf2f(u16 v) {
  union { u32 u; float f; } t; t.u = ((u32)v) << 16; return t.f;
}
__device__ __forceinline__ u16 f2bf(float f) {
  union { float f; u32 u; } t; t.f = f;
  u32 u = t.u + 0x7fffu + ((t.u >> 16) & 1u);   // RNE
  return (u16)(u >> 16);
}
__device__ __forceinline__ void g2lds16(const void* g, void* l) {
  __builtin_amdgcn_global_load_lds((const __attribute__((address_space(1))) void*)g,
                                   (__attribute__((address_space(3))) void*)l,
                                   16, 0, 0);
}

// ---------------------------------------------------------------------------
// x [16384][1024] fp32 -> bf16, flat
// ---------------------------------------------------------------------------
__global__ __launch_bounds__(256) void canon_x(
    const float* __restrict__ xf, u16* __restrict__ xb) {
  size_t i = ((size_t)blockIdx.x * 256 + threadIdx.x) * 8;
  float4 a = *(const float4*)(xf + i);
  float4 b = *(const float4*)(xf + i + 4);
  u16 o[8] = { f2bf(a.x), f2bf(a.y), f2bf(a.z), f2bf(a.w),
               f2bf(b.x), f2bf(b.y), f2bf(b.z), f2bf(b.w) };
  *(bf16x8*)(xb + i) = *(bf16x8*)o;
}

// ---------------------------------------------------------------------------
// Weight transpose+convert: in [R][C] fp32 -> out [C][R] bf16
// ---------------------------------------------------------------------------
__global__ __launch_bounds__(256) void transpose_w(
    const float* __restrict__ in, u16* __restrict__ out, int R, int C) {
  __shared__ u16 tile[32][33];
  int c0 = blockIdx.x * 32, r0 = blockIdx.y * 32;
  int tx = threadIdx.x & 31, ty = threadIdx.x >> 5;
#pragma unroll
  for (int i = 0; i < 32; i += 8)
    tile[ty + i][tx] = f2bf(in[(size_t)(r0 + ty + i) * C + c0 + tx]);
  __syncthreads();
#pragma unroll
  for (int i = 0; i < 32; i += 8)
    out[(size_t)(c0 + ty + i) * R + r0 + tx] = tile[tx][ty + i];
}

// ---------------------------------------------------------------------------
// V part of qkv [16384][3072] -> Vt [bh=512][d=64][t=512]   (bf16)
// ---------------------------------------------------------------------------
__global__ __launch_bounds__(256) void transpose_v(
    const u16* __restrict__ qkv, u16* __restrict__ vt) {
  __shared__ u16 tile[32][33];
  int bh = blockIdx.z, bn = bh >> 4, h = bh & 15;
  int t0 = blockIdx.x * 32, d0 = blockIdx.y * 32;
  int tx = threadIdx.x & 31, ty = threadIdx.x >> 5;
  const u16* src = qkv + (size_t)(bn * 512) * 3072 + 2048 + h * 64;
#pragma unroll
  for (int i = 0; i < 32; i += 8)
    tile[ty + i][tx] = src[(size_t)(t0 + ty + i) * 3072 + d0 + tx];
  __syncthreads();
  u16* dst = vt + ((size_t)bh * 64 + d0) * 512 + t0;
#pragma unroll
  for (int i = 0; i < 32; i += 8)
    dst[(size_t)(ty + i) * 512 + tx] = tile[tx][ty + i];
}

// ---------------------------------------------------------------------------
// C[M,N] = A[M,K](bf16) * Bt[N,K]^T(bf16) + bias[N](fp32); OutT u16|float.
// m97 structure: 128x128 tile, BK=32, 2x2 waves of 64x64, global_load_lds w=16.
// R10: XCD-aware block swizzle (T1); requires gridX*gridY % 8 == 0 (holds:
// 24*128=3072, 8*128=1024).
// ---------------------------------------------------------------------------
template <typename OutT>
__global__ __launch_bounds__(256, 2) void gemm_bt_bias(
    const u16* __restrict__ A, const u16* __restrict__ Bt,
    const float* __restrict__ bias, OutT* __restrict__ C,
    int M, int N, int K) {
  __shared__ __align__(16) u16 As[128 * 32];
  __shared__ __align__(16) u16 Bs[128 * 32];
  const int tid = threadIdx.x;
  const int wave = tid >> 6, lane = tid & 63;
  const int quad = lane >> 4, l16 = lane & 15;

  // T1: dispatch index -> logical block, contiguous chunk per XCD.
  const int nbx = gridDim.x;
  const int ntot = nbx * gridDim.y;
  const int flat = blockIdx.y * nbx + blockIdx.x;
  const int swz = (flat & 7) * (ntot >> 3) + (flat >> 3);
  const int m0 = (swz / nbx) * 128, n0 = (swz % nbx) * 128;
  const int wm = (wave >> 1) * 64, wn = (wave & 1) * 64;

  f32x4 acc[4][4] = {};

  int e0 = (wave * 512) + lane * 8;   // chunk 0 element offset in 128x32 tile
  int e1 = 2048 + e0;                 // chunk 1
  int rA0 = e0 >> 5, cA0 = e0 & 31;
  int rA1 = e1 >> 5, cA1 = e1 & 31;
  const u16* ga0 = A + (size_t)(m0 + rA0) * K + cA0;
  const u16* ga1 = A + (size_t)(m0 + rA1) * K + cA1;
  const u16* gb0 = Bt + (size_t)(n0 + rA0) * K + cA0;
  const u16* gb1 = Bt + (size_t)(n0 + rA1) * K + cA1;
  u16* As0 = As + (size_t)wave * 512;
  u16* As1 = As0 + 2048;
  u16* Bs0 = Bs + (size_t)wave * 512;
  u16* Bs1 = Bs0 + 2048;

  for (int k0 = 0; k0 < K; k0 += 32) {
    g2lds16(ga0 + k0, As0);
    g2lds16(ga1 + k0, As1);
    g2lds16(gb0 + k0, Bs0);
    g2lds16(gb1 + k0, Bs1);
    __syncthreads();
    bf16x8 a[4], b[4];
#pragma unroll
    for (int mi = 0; mi < 4; ++mi)
      a[mi] = *(const bf16x8*)(As + (wm + mi * 16 + l16) * 32 + quad * 8);
#pragma unroll
    for (int ni = 0; ni < 4; ++ni)
      b[ni] = *(const bf16x8*)(Bs + (wn + ni * 16 + l16) * 32 + quad * 8);
#pragma unroll
    for (int mi = 0; mi < 4; ++mi)
#pragma unroll
      for (int ni = 0; ni < 4; ++ni)
        acc[mi][ni] = __builtin_amdgcn_mfma_f32_16x16x32_bf16(a[mi], b[ni], acc[mi][ni], 0, 0, 0);
    __syncthreads();
  }

  // epilogue: C/D layout col=l16, row=quad*4+reg
#pragma unroll
  for (int ni = 0; ni < 4; ++ni) {
    int col = n0 + wn + ni * 16 + l16;
    float bv = bias[col];
#pragma unroll
    for (int mi = 0; mi < 4; ++mi) {
      int row = m0 + wm + mi * 16 + quad * 4;
#pragma unroll
      for (int r = 0; r < 4; ++r) {
        float v = acc[mi][ni][r] + bv;
        if constexpr (sizeof(OutT) == 2)
          C[(size_t)(row + r) * N + col] = f2bf(v);
        else
          C[(size_t)(row + r) * N + col] = v;
      }
    }
  }
}

// ---------------------------------------------------------------------------
// Windowed causal flash attention. Grid (qt=4, h=16, bn=32), 256 threads.
// R10: counted-vmcnt pipeline, raw s_barrier (no __syncthreads in loop).
//   barA (Ks free) -> DMA K(j+1) -> softmax -> vmcnt(4)/barD (V(j) landed)
//   -> P+PV -> vmcnt(0)/barB (Vs free, K(j+1) landed) -> DMA V(j+1).
// All barrier paths wave-uniform. Per-wave vmcnt + barrier => all waves'
// DMA landed. sched_barrier(0) after each barrier pins LDS-read ordering.
// LDS 48KB; VGPR ~116 -> 3 blocks/CU.
// ---------------------------------------------------------------------------
__global__ __launch_bounds__(256, 2) void attn_win(
    const u16* __restrict__ qkv, const u16* __restrict__ vt,
    u16* __restrict__ attn) {
  __shared__ __align__(16) u16 Ks[128 * 64];
  __shared__ __align__(16) u16 Vs[64 * 128];
  __shared__ __align__(16) u16 Ps[4][16 * 128];

  const int qt = blockIdx.x, h = blockIdx.y, bn = blockIdx.z;
  const int bh = bn * 16 + h;
  const int tid = threadIdx.x;
  const int wave = tid >> 6, lane = tid & 63;
  const int quad = lane >> 4, l16 = lane & 15;
  const int t0 = bn * 512 + qt * 128;

  // ---- Q operand fragments in registers (R6-verified layout) ----
  bf16x8 aq[2][2];
#pragma unroll
  for (int mi = 0; mi < 2; ++mi)
#pragma unroll
    for (int ks = 0; ks < 2; ++ks)
      aq[mi][ks] = *(const bf16x8*)(
          qkv + (size_t)(t0 + wave * 32 + mi * 16 + l16) * 3072 + h * 64 + ks * 32 + quad * 8);

  // ---- staging helpers (R9-verified addressing): pre-swizzled source,
  //      linear LDS dest (wave-uniform base + lane*16B). 4 g2lds each. ----
  const int rk0 = tid >> 3, ck0 = tid & 7;
  const int rv0 = tid >> 4, cv0 = tid & 15;

#define STAGE_K(JT)                                                           \
  {                                                                           \
    const int tk_ = bn * 512 + (JT) * 128;                                    \
    _Pragma("unroll")                                                         \
    for (int it = 0; it < 4; ++it) {                                          \
      int rk = it * 32 + rk0;                                                 \
      const u16* gk = qkv + (size_t)(tk_ + rk) * 3072 + 1024 + h * 64 +       \
                      ((ck0 ^ (rk & 7)) * 8);                                 \
      g2lds16(gk, Ks + (size_t)(it * 256 + wave * 64) * 8);                   \
    }                                                                         \
  }
#define STAGE_V(JT)                                                           \
  {                                                                           \
    _Pragma("unroll")                                                         \
    for (int it = 0; it < 4; ++it) {                                          \
      int rv = it * 16 + rv0;                                                 \
      const u16* gv = vt + ((size_t)bh * 64 + rv) * 512 + (JT) * 128 +        \
                      ((cv0 ^ (rv & 15)) * 8);                                \
      g2lds16(gv, Vs + (size_t)(it * 256 + wave * 64) * 8);                   \
    }                                                                         \
  }

  // ---- prologue: stage tile 0; wait K only (V waited at first barD) ----
  STAGE_K(0);                       // vmcnt 4 oldest
  STAGE_V(0);                       // vmcnt 8
  asm volatile("s_waitcnt vmcnt(4)" ::: "memory");   // K(0) landed
  __builtin_amdgcn_s_barrier();
  __builtin_amdgcn_sched_barrier(0);

  float mrun[2][4], lrun[2][4];
  f32x4 o[2][4] = {};
#pragma unroll
  for (int mi = 0; mi < 2; ++mi)
#pragma unroll
    for (int r = 0; r < 4; ++r) { mrun[mi][r] = -1e30f; lrun[mi][r] = 0.f; }

  const float cexp = 0.18033688011112042f;  // (1/sqrt(64)) * log2(e)

  u16* pw = &Ps[wave][0];

  for (int j = 0; j <= qt; ++j) {
    // ---- S = Q K^T (this wave: rows [wave*32, +32)) ----
    f32x4 s[2][8] = {};
    __builtin_amdgcn_s_setprio(1);
#pragma unroll
    for (int ks = 0; ks < 2; ++ks) {
#pragma unroll
      for (int ni = 0; ni < 8; ++ni) {
        int n = ni * 16 + l16;
        bf16x8 bk = *(const bf16x8*)(Ks + n * 64 + (((ks * 4 + quad) ^ (n & 7)) * 8));
        s[0][ni] = __builtin_amdgcn_mfma_f32_16x16x32_bf16(aq[0][ks], bk, s[0][ni], 0, 0, 0);
        s[1][ni] = __builtin_amdgcn_mfma_f32_16x16x32_bf16(aq[1][ks], bk, s[1][ni], 0, 0, 0);
      }
    }
    __builtin_amdgcn_s_setprio(0);

    // ---- barrier A: all waves done reading Ks (operands consumed) ----
    __builtin_amdgcn_s_barrier();
    __builtin_amdgcn_sched_barrier(0);
    if (j < qt) STAGE_K(j + 1);       // DMA into Ks; hides under softmax+PV

    // ---- online softmax (C layout: col=l16, row=quad*4+r) ----
    const bool diag = (j == qt);
#pragma unroll
    for (int mi = 0; mi < 2; ++mi) {
#pragma unroll
      for (int r = 0; r < 4; ++r) {
        int m = wave * 32 + mi * 16 + quad * 4 + r;
        float rmax = -1e30f;
#pragma unroll
        for (int ni = 0; ni < 8; ++ni) {
          float v = s[mi][ni][r] * cexp;
          if (diag && (ni * 16 + l16 > m)) v = -1e30f;
          s[mi][ni][r] = v;
          rmax = fmaxf(rmax, v);
        }
        rmax = fmaxf(rmax, __shfl_xor(rmax, 1));
        rmax = fmaxf(rmax, __shfl_xor(rmax, 2));
        rmax = fmaxf(rmax, __shfl_xor(rmax, 4));
        rmax = fmaxf(rmax, __shfl_xor(rmax, 8));
        float mnew = fmaxf(mrun[mi][r], rmax);
        float alpha = exp2f(mrun[mi][r] - mnew);
        mrun[mi][r] = mnew;
        float rsum = 0.f;
#pragma unroll
        for (int ni = 0; ni < 8; ++ni) {
          float pv = exp2f(s[mi][ni][r] - mnew);
          s[mi][ni][r] = pv;
          rsum += pv;
        }
        rsum += __shfl_xor(rsum, 1);
        rsum += __shfl_xor(rsum, 2);
        rsum += __shfl_xor(rsum, 4);
        rsum += __shfl_xor(rsum, 8);
        lrun[mi][r] = lrun[mi][r] * alpha + rsum;
#pragma unroll
        for (int di = 0; di < 4; ++di) o[mi][di][r] *= alpha;
      }
    }

    // ---- barrier D: V(j) landed (V loads are the 4 oldest of <=8) ----
    if (j < qt) { asm volatile("s_waitcnt vmcnt(4)" ::: "memory"); }
    else        { asm volatile("s_waitcnt vmcnt(0)" ::: "memory"); }
    __builtin_amdgcn_s_barrier();
    __builtin_amdgcn_sched_barrier(0);

    // ---- two 16-row halves: P-write (wave-private) then PV ----
#pragma unroll
    for (int mi = 0; mi < 2; ++mi) {
#pragma unroll
      for (int ni = 0; ni < 8; ++ni)
#pragma unroll
        for (int r = 0; r < 4; ++r) {
          int row = quad * 4 + r;               // 0..15 within this half
          int col = ni * 16 + l16;
          int phys = (col >> 3) ^ row;
          pw[row * 128 + phys * 8 + (col & 7)] = f2bf(s[mi][ni][r]);
        }

      __builtin_amdgcn_s_setprio(1);
#pragma unroll
      for (int ksv = 0; ksv < 4; ++ksv) {
        bf16x8 ap = *(const bf16x8*)(pw + l16 * 128 + (((ksv * 4 + quad) ^ l16) * 8));
#pragma unroll
        for (int di = 0; di < 4; ++di) {
          int n = di * 16 + l16;
          bf16x8 bv = *(const bf16x8*)(Vs + n * 128 + (((ksv * 4 + quad) ^ (n & 15)) * 8));
          o[mi][di] = __builtin_amdgcn_mfma_f32_16x16x32_bf16(ap, bv, o[mi][di], 0, 0, 0);
        }
      }
      __builtin_amdgcn_s_setprio(0);
    }

    // ---- barrier B: all waves done reading Vs; K(j+1) landed ----
    asm volatile("s_waitcnt vmcnt(0)" ::: "memory");   // cheap: K had ~full tile
    __builtin_amdgcn_s_barrier();
    __builtin_amdgcn_sched_barrier(0);
    if (j < qt) STAGE_V(j + 1);       // DMA into Vs; hides under next QK+softmax
  }
#undef STAGE_K
#undef STAGE_V

  // ---- epilogue: O / l -> attn [token][h*64+d] (bf16) ----
#pragma unroll
  for (int mi = 0; mi < 2; ++mi)
#pragma unroll
    for (int r = 0; r < 4; ++r) {
      float inv = 1.0f / lrun[mi][r];
      int trow = t0 + wave * 32 + mi * 16 + quad * 4 + r;
#pragma unroll
      for (int di = 0; di < 4; ++di)
        attn[(size_t)trow * 1024 + h * 64 + di * 16 + l16] = f2bf(o[mi][di][r] * inv);
    }
}

// ---------------------------------------------------------------------------
extern "C" void kernel_launch(void* const* d_in, const int* in_sizes, int n_in,
                              void* d_out, int out_size, void* d_ws, size_t ws_size,
                              hipStream_t stream) {
  (void)in_sizes; (void)n_in; (void)out_size; (void)ws_size;
  const float* x     = (const float*)d_in[0];   // [16384][1024] fp32
  const float* w_qkv = (const float*)d_in[1];   // [1024][3072] fp32
  const float* b_qkv = (const float*)d_in[2];   // [3072] fp32
  const float* w_o   = (const float*)d_in[3];   // [1024][1024] fp32
  const float* b_o   = (const float*)d_in[4];   // [1024] fp32
  float* out = (float*)d_out;                   // [16384][1024] fp32

  char* ws = (char*)d_ws;
  u16* qkv   = (u16*)(ws + 0);            // 96 MB
  u16* vtb   = (u16*)(ws + 100663296);    // 32 MB
  u16* attnb = (u16*)(ws + 134217728);    // 32 MB
  u16* xb    = (u16*)(ws + 167772160);    // 32 MB
  u16* wqkvT = (u16*)(ws + 201326592);    // 6 MB
  u16* woT   = (u16*)(ws + 207618048);    // 2 MB  (total 200 MB)

  canon_x<<<8192, 256, 0, stream>>>(x, xb);
  transpose_w<<<dim3(96, 32), 256, 0, stream>>>(w_qkv, wqkvT, 1024, 3072);
  transpose_w<<<dim3(32, 32), 256, 0, stream>>>(w_o, woT, 1024, 1024);

  gemm_bt_bias<u16><<<dim3(24, 128), 256, 0, stream>>>(
      xb, wqkvT, b_qkv, qkv, 16384, 3072, 1024);
  transpose_v<<<dim3(16, 2, 512), 256, 0, stream>>>(qkv, vtb);
  attn_win<<<dim3(4, 16, 32), 256, 0, stream>>>(qkv, vtb, attnb);
  gemm_bt_bias<float><<<dim3(8, 128), 256, 0, stream>>>(
      attnb, woT, b_o, out, 16384, 1024, 1024);
}